// Round 8
// baseline (367.354 us; speedup 1.0000x reference)
//
#include <hip/hip_runtime.h>
#include <hip/hip_bf16.h>
#include <stdint.h>
#include <math.h>

typedef __attribute__((ext_vector_type(4))) float f32x4;
typedef __attribute__((ext_vector_type(8))) short s16x8;

#define MFMA16(a,b,c) __builtin_amdgcn_mfma_f32_16x16x32_bf16((a),(b),(c),0,0,0)

#define Cc 256
#define Nc 4096
#define SCALE_F 0.17677669529663688f

__device__ __forceinline__ uint16_t f2bf(float x){
  uint32_t u = __float_as_uint(x);
  return (uint16_t)((u + 0x7fffu + ((u >> 16) & 1u)) >> 16);
}
__device__ __forceinline__ float bf2f(uint16_t b){
  return __uint_as_float(((uint32_t)b) << 16);
}

// ---------------- K0: split weights into bf16 hi/lo ----------------
extern "C" __global__ __launch_bounds__(256) void k0_prep(
    const float* __restrict__ qw, const float* __restrict__ kw, const float* __restrict__ vw,
    uint16_t* __restrict__ qwh, uint16_t* __restrict__ qwl,
    uint16_t* __restrict__ kwh, uint16_t* __restrict__ kwl,
    uint16_t* __restrict__ vwb)
{
  int i = blockIdx.x * 256 + threadIdx.x;
  float q = qw[i]; uint16_t qh = f2bf(q);
  qwh[i] = qh; qwl[i] = f2bf(q - bf2f(qh));
  float k = kw[i]; uint16_t kh = f2bf(k);
  kwh[i] = kh; kwl[i] = f2bf(k - bf2f(kh));
  vwb[i] = f2bf(vw[i]);
}

// ---------------- K1: fused Q,K,V GEMM + spike + BN partials ----------------
// grid (128 nb, 2 oh, 16 b), 256 threads (4 waves). Block: 32-n tile, 128-o half.
// x tile staged in LDS in MFMA-fragment order (16B unit per lane), bf16 hi/lo.
// Epilogues transpose via per-wave LDS scratch for full-line coalesced stores.
extern "C" __global__ __launch_bounds__(256, 4) void k1_qkv(
    const float* __restrict__ x,
    const uint16_t* __restrict__ qwh, const uint16_t* __restrict__ qwl,
    const uint16_t* __restrict__ kwh, const uint16_t* __restrict__ kwl,
    const uint16_t* __restrict__ vwb,
    const float* __restrict__ qvth, const float* __restrict__ kvth,
    uint16_t* __restrict__ qs, uint16_t* __restrict__ ks,
    uint16_t* __restrict__ v0t,
    float* __restrict__ psum, float* __restrict__ psq)
{
  __shared__ __align__(16) uint16_t XS[16384];  // XH = XS[0:8192), XL = XS[8192:16384)
  __shared__ float vq_s[128];
  __shared__ float vk_s[128];

  const int tid  = threadIdx.x;
  const int lane = tid & 63, wid = tid >> 6;
  const int l15  = lane & 15, lg = lane >> 4;
  const int nb = blockIdx.x, oh = blockIdx.y, b = blockIdx.z;
  const int OH = oh * 128;
  const int wrow = OH + wid * 32;
  const int nbase = nb * 32;

  if (tid < 128) vq_s[tid] = qvth[OH + tid];
  else           vk_s[tid - 128] = kvth[OH + tid - 128];

  uint16_t* XH = XS;
  uint16_t* XL = XS + 8192;

  // ---- stage x tile (32 n x 256 c), fragment-ordered, bf16 hi/lo ----
  #pragma unroll
  for (int ni_s = 0; ni_s < 2; ++ni_s){
    #pragma unroll
    for (int kst = 0; kst < 2; ++kst){
      const int n  = ni_s * 16 + l15;
      const int c0 = wid * 64 + kst * 32 + lg * 8;
      const float* xp = x + ((size_t)(b * Cc + c0)) * Nc + nbase + n;
      s16x8 vh, vl;
      #pragma unroll
      for (int j = 0; j < 8; ++j){
        float v = xp[(size_t)j * Nc];
        uint16_t h = f2bf(v);
        vh[j] = (short)h;
        vl[j] = (short)f2bf(v - bf2f(h));
      }
      const int U = ((wid * 2 + kst) * 2 + ni_s) * 64 + l15 + lg * 16;
      *(s16x8*)&XH[U * 8] = vh;
      *(s16x8*)&XL[U * 8] = vl;
    }
  }
  __syncthreads();

  const f32x4 fz = {0.f, 0.f, 0.f, 0.f};

  // ---- Q,K phase: 3-pass bf16x2 (hi*hi + hi*lo + lo*hi) ----
  f32x4 accq[2][2], acck[2][2];
  #pragma unroll
  for (int mi = 0; mi < 2; ++mi)
    #pragma unroll
    for (int ni = 0; ni < 2; ++ni){ accq[mi][ni] = fz; acck[mi][ni] = fz; }

  for (int kc = 0; kc < 256; kc += 32){
    const int g = kc >> 5;
    s16x8 bh[2], bl[2];
    #pragma unroll
    for (int ni = 0; ni < 2; ++ni){
      bh[ni] = *(const s16x8*)&XH[((g * 2 + ni) * 64 + lane) * 8];
      bl[ni] = *(const s16x8*)&XL[((g * 2 + ni) * 64 + lane) * 8];
    }
    #pragma unroll
    for (int mi = 0; mi < 2; ++mi){
      const int wa = (wrow + mi * 16 + l15) * Cc + kc + lg * 8;
      s16x8 aqh = *(const s16x8*)&qwh[wa];
      s16x8 aql = *(const s16x8*)&qwl[wa];
      s16x8 akh = *(const s16x8*)&kwh[wa];
      s16x8 akl = *(const s16x8*)&kwl[wa];
      #pragma unroll
      for (int ni = 0; ni < 2; ++ni){
        accq[mi][ni] = MFMA16(aqh, bh[ni], accq[mi][ni]);
        accq[mi][ni] = MFMA16(aqh, bl[ni], accq[mi][ni]);
        accq[mi][ni] = MFMA16(aql, bh[ni], accq[mi][ni]);
        acck[mi][ni] = MFMA16(akh, bh[ni], acck[mi][ni]);
        acck[mi][ni] = MFMA16(akh, bl[ni], acck[mi][ni]);
        acck[mi][ni] = MFMA16(akl, bh[ni], acck[mi][ni]);
      }
    }
  }
  __syncthreads();   // all waves done reading XL; reuse as per-wave scratch

  // ---- spike epilogue via per-wave transpose scratch (coalesced stores) ----
  {
    float* sscr = (float*)XL + wid * (16 * 36);
    const int o_ = lane >> 2;
    const int nloc = (lane & 3) * 8;
    #pragma unroll
    for (int mi = 0; mi < 2; ++mi){
      const int o = wrow + mi * 16 + o_;
      // q
      #pragma unroll
      for (int ni = 0; ni < 2; ++ni)
        #pragma unroll
        for (int r = 0; r < 4; ++r)
          sscr[(lg * 4 + r) * 36 + ni * 16 + l15] = accq[mi][ni][r];
      {
        const float* sp = sscr + o_ * 36 + nloc;
        const float vq = vq_s[o - OH];
        s16x8 pk;
        #pragma unroll
        for (int j = 0; j < 8; ++j){
          float v = sp[j];
          float s = (v >= vq ? 1.f : 0.f) - (v <= -vq ? 1.f : 0.f);
          pk[j] = (short)f2bf(s);
        }
        *(s16x8*)&qs[((size_t)(b * Cc + o)) * Nc + nbase + nloc] = pk;
      }
      // k
      #pragma unroll
      for (int ni = 0; ni < 2; ++ni)
        #pragma unroll
        for (int r = 0; r < 4; ++r)
          sscr[(lg * 4 + r) * 36 + ni * 16 + l15] = acck[mi][ni][r];
      {
        const float* sp = sscr + o_ * 36 + nloc;
        const float vk = vk_s[o - OH];
        s16x8 pk;
        #pragma unroll
        for (int j = 0; j < 8; ++j){
          float v = sp[j];
          float s = (v >= vk ? 1.f : 0.f) - (v <= -vk ? 1.f : 0.f);
          pk[j] = (short)f2bf(s);
        }
        *(s16x8*)&ks[((size_t)(b * Cc + o)) * Nc + nbase + nloc] = pk;
      }
    }
  }

  // ---- V phase: single-pass bf16 (reads XH only) ----
  f32x4 accv[2][2];
  #pragma unroll
  for (int mi = 0; mi < 2; ++mi)
    #pragma unroll
    for (int ni = 0; ni < 2; ++ni) accv[mi][ni] = fz;

  for (int kc = 0; kc < 256; kc += 32){
    const int g = kc >> 5;
    s16x8 bh[2];
    #pragma unroll
    for (int ni = 0; ni < 2; ++ni)
      bh[ni] = *(const s16x8*)&XH[((g * 2 + ni) * 64 + lane) * 8];
    #pragma unroll
    for (int mi = 0; mi < 2; ++mi){
      s16x8 av = *(const s16x8*)&vwb[(wrow + mi * 16 + l15) * Cc + kc + lg * 8];
      #pragma unroll
      for (int ni = 0; ni < 2; ++ni)
        accv[mi][ni] = MFMA16(av, bh[ni], accv[mi][ni]);
    }
  }

  // ---- BN partials: psum layout [c][bid] for coalesced K2 reads ----
  const int bid = b * 128 + nb;
  #pragma unroll
  for (int mi = 0; mi < 2; ++mi){
    #pragma unroll
    for (int r = 0; r < 4; ++r){
      float s1 = 0.f, s2 = 0.f;
      #pragma unroll
      for (int ni = 0; ni < 2; ++ni){
        const float v = accv[mi][ni][r];
        s1 += v; s2 += v * v;
      }
      #pragma unroll
      for (int mk = 1; mk < 16; mk <<= 1){
        s1 += __shfl_xor(s1, mk);
        s2 += __shfl_xor(s2, mk);
      }
      if (l15 == 0){
        const int o = wrow + mi * 16 + lg * 4 + r;
        psum[(size_t)o * 2048 + bid] = s1;
        psq [(size_t)o * 2048 + bid] = s2;
      }
    }
  }
  __syncthreads();   // all waves done with XH; reuse whole XS as scratch

  // ---- v0t transpose: per-wave scratch, 32B/lane stores (64B lines) ----
  {
    float* tscr = (float*)XS + wid * (32 * 36);
    #pragma unroll
    for (int mi = 0; mi < 2; ++mi)
      #pragma unroll
      for (int ni = 0; ni < 2; ++ni)
        #pragma unroll
        for (int r = 0; r < 4; ++r)
          tscr[(mi * 16 + lg * 4 + r) * 36 + ni * 16 + l15] = accv[mi][ni][r];
    const int n = lane >> 1, half = lane & 1;
    s16x8 o0, o1;
    #pragma unroll
    for (int k = 0; k < 8; ++k){
      o0[k] = (short)f2bf(tscr[(half * 16 + k) * 36 + n]);
      o1[k] = (short)f2bf(tscr[(half * 16 + 8 + k) * 36 + n]);
    }
    uint16_t* dst = v0t + ((size_t)(b * Nc + nbase + n)) * Cc + wrow + half * 16;
    *(s16x8*)dst = o0;
    *(s16x8*)(dst + 8) = o1;
  }
}

// ---------------- K2: finalize BN (256 blocks, coalesced) ----------------
extern "C" __global__ __launch_bounds__(256) void k2_stats(
    const float* __restrict__ psum, const float* __restrict__ psq,
    const float* __restrict__ gamma, const float* __restrict__ beta,
    float* __restrict__ sc, float* __restrict__ sh)
{
  __shared__ float w1[4], w2[4];
  const int c = blockIdx.x;
  const int tid = threadIdx.x;
  const float* p1 = psum + (size_t)c * 2048 + tid * 8;
  const float* p2 = psq  + (size_t)c * 2048 + tid * 8;
  f32x4 a0 = *(const f32x4*)p1,  a1 = *(const f32x4*)(p1 + 4);
  f32x4 b0 = *(const f32x4*)p2,  b1 = *(const f32x4*)(p2 + 4);
  float s1 = a0[0]+a0[1]+a0[2]+a0[3] + a1[0]+a1[1]+a1[2]+a1[3];
  float s2 = b0[0]+b0[1]+b0[2]+b0[3] + b1[0]+b1[1]+b1[2]+b1[3];
  #pragma unroll
  for (int mk = 1; mk < 64; mk <<= 1){
    s1 += __shfl_xor(s1, mk);
    s2 += __shfl_xor(s2, mk);
  }
  if ((tid & 63) == 0){ w1[tid >> 6] = s1; w2[tid >> 6] = s2; }
  __syncthreads();
  if (tid == 0){
    float t1 = w1[0]+w1[1]+w1[2]+w1[3];
    float t2 = w2[0]+w2[1]+w2[2]+w2[3];
    const float inv = 1.f / 65536.f;
    const float mean = t1 * inv;
    const float var  = t2 * inv - mean * mean;
    const float s = gamma[c] * rsqrtf(var + 1e-5f);
    sc[c] = s;
    sh[c] = beta[c] - mean * s;
  }
}

// ---------------- K3a: QK^T partials (exact), n-split, LDS-staged ----------------
// grid (8 h, 16 b, 8 ns), 256 threads (4 waves). Block does 512 n in 2 chunks of 256.
// LDS: 36 KiB (QK staging 32 KiB; partial-combine needs 4*1056 floats = 16.5 KiB).
extern "C" __global__ __launch_bounds__(256) void k3a_qk(
    const uint16_t* __restrict__ qs, const uint16_t* __restrict__ ks,
    float* __restrict__ Sbuf)
{
  __shared__ __align__(16) uint16_t QK[18432];  // q=[0:8192), k=[8192:16384), +4KiB slack for Sp
  const int h = blockIdx.x, b = blockIdx.y, ns = blockIdx.z;
  const int tid = threadIdx.x;
  const int lane = tid & 63, w = tid >> 6;

  uint16_t* qlds = QK;
  uint16_t* klds = QK + 8192;

  const f32x4 fz = {0.f, 0.f, 0.f, 0.f};
  f32x4 acc[2][2] = {{fz, fz}, {fz, fz}};
  const uint16_t* qb = qs + ((size_t)(b * Cc + h * 32)) * Nc;
  const uint16_t* kb = ks + ((size_t)(b * Cc + h * 32)) * Nc;

  const int row = tid & 31, seg = tid >> 5;   // staging role
  for (int cc = 0; cc < 2; ++cc){
    const int n0 = ns * 512 + cc * 256;
    // stage q,k chunk, fragment-ordered
    const uint16_t* qsrc = qb + (size_t)row * Nc + n0 + seg * 32;
    const uint16_t* ksrc = kb + (size_t)row * Nc + n0 + seg * 32;
    #pragma unroll
    for (int i = 0; i < 4; ++i){
      const int U = (seg * 2 + (row >> 4)) * 64 + (row & 15) + i * 16;
      *(s16x8*)&qlds[U * 8] = *(const s16x8*)(qsrc + i * 8);
      *(s16x8*)&klds[U * 8] = *(const s16x8*)(ksrc + i * 8);
    }
    __syncthreads();
    #pragma unroll
    for (int kci = 0; kci < 2; ++kci){
      const int g = w * 2 + kci;
      s16x8 a0 = *(const s16x8*)&qlds[((g * 2 + 0) * 64 + lane) * 8];
      s16x8 a1 = *(const s16x8*)&qlds[((g * 2 + 1) * 64 + lane) * 8];
      s16x8 b0 = *(const s16x8*)&klds[((g * 2 + 0) * 64 + lane) * 8];
      s16x8 b1 = *(const s16x8*)&klds[((g * 2 + 1) * 64 + lane) * 8];
      acc[0][0] = MFMA16(a0, b0, acc[0][0]);
      acc[0][1] = MFMA16(a0, b1, acc[0][1]);
      acc[1][0] = MFMA16(a1, b0, acc[1][0]);
      acc[1][1] = MFMA16(a1, b1, acc[1][1]);
    }
    __syncthreads();
  }

  // combine 4 waves, write partial (exact integer-valued f32 sums)
  float* Sp = (float*)QK;   // 4 * 1056 floats = 16.5 KiB, fits in 36 KiB QK
  const int l15 = lane & 15, lg = lane >> 4;
  #pragma unroll
  for (int di = 0; di < 2; ++di)
    #pragma unroll
    for (int ei = 0; ei < 2; ++ei)
      #pragma unroll
      for (int r = 0; r < 4; ++r)
        Sp[w * 1056 + (di * 16 + lg * 4 + r) * 33 + ei * 16 + l15] = acc[di][ei][r];
  __syncthreads();
  for (int idx = tid; idx < 1024; idx += 256){
    const int d = idx >> 5, e = idx & 31;
    float s = Sp[0 * 1056 + d * 33 + e] + Sp[1 * 1056 + d * 33 + e]
            + Sp[2 * 1056 + d * 33 + e] + Sp[3 * 1056 + d * 33 + e];
    Sbuf[((size_t)(ns * 128 + b * 8 + h)) * 1024 + idx] = s;
  }
}

// ---------------- K3b: sum partials + softmax + fold into M(bf16), bias ----------------
// grid (8 h, 16 b), 256 threads (4 waves).
extern "C" __global__ __launch_bounds__(256) void k3b_sm(
    const float* __restrict__ Sbuf, const float* __restrict__ pw,
    const float* __restrict__ sc, const float* __restrict__ sh,
    uint16_t* __restrict__ Mp16, float* __restrict__ bias)
{
  __shared__ float Sf[32 * 33];
  __shared__ __align__(16) uint16_t attn_t[32 * 40];  // [e][d] bf16

  const int h = blockIdx.x, b = blockIdx.y;
  const int tid = threadIdx.x;
  const int lane = tid & 63, w = tid >> 6;
  const int l15 = lane & 15, lg = lane >> 4;

  for (int idx = tid; idx < 1024; idx += 256){
    float s = 0.f;
    #pragma unroll
    for (int ns = 0; ns < 8; ++ns)
      s += Sbuf[((size_t)(ns * 128 + b * 8 + h)) * 1024 + idx];
    Sf[(idx >> 5) * 33 + (idx & 31)] = s * SCALE_F;
  }
  __syncthreads();

  if (tid < 32){
    const int d = tid;
    float mx = -1e30f;
    #pragma unroll
    for (int e = 0; e < 32; ++e) mx = fmaxf(mx, Sf[d * 33 + e]);
    float p[32]; float sum = 0.f;
    #pragma unroll
    for (int e = 0; e < 32; ++e){ p[e] = expf(Sf[d * 33 + e] - mx); sum += p[e]; }
    const float inv = 1.f / sum;
    #pragma unroll
    for (int e = 0; e < 32; ++e) attn_t[e * 40 + d] = f2bf(p[e] * inv);
  }
  __syncthreads();

  s16x8 bfr[2];
  #pragma unroll
  for (int ei = 0; ei < 2; ++ei)
    bfr[ei] = *(const s16x8*)&attn_t[(ei * 16 + l15) * 40 + lg * 8];

  const f32x4 fz = {0.f, 0.f, 0.f, 0.f};
  f32x4 m[4][2];
  #pragma unroll
  for (int mi = 0; mi < 4; ++mi){
    m[mi][0] = fz; m[mi][1] = fz;
    const float* ap = pw + ((size_t)(w * 64 + mi * 16 + l15)) * Cc + h * 32 + lg * 8;
    f32x4 a0 = *(const f32x4*)ap;
    f32x4 a1 = *(const f32x4*)(ap + 4);
    s16x8 af;
    #pragma unroll
    for (int j = 0; j < 4; ++j){ af[j] = (short)f2bf(a0[j]); af[4 + j] = (short)f2bf(a1[j]); }
    #pragma unroll
    for (int ei = 0; ei < 2; ++ei)
      m[mi][ei] = MFMA16(af, bfr[ei], m[mi][ei]);
  }

  const float sc0 = sc[h * 32 + l15],      sc1 = sc[h * 32 + 16 + l15];
  const float sh0 = sh[h * 32 + l15],      sh1 = sh[h * 32 + 16 + l15];
  #pragma unroll
  for (int mi = 0; mi < 4; ++mi){
    #pragma unroll
    for (int r = 0; r < 4; ++r){
      const int o = w * 64 + mi * 16 + lg * 4 + r;
      uint16_t* mp = Mp16 + ((size_t)(b * Cc + o)) * Cc + h * 32;
      const float m0 = m[mi][0][r], m1 = m[mi][1][r];
      mp[l15]      = f2bf(m0 * sc0);
      mp[16 + l15] = f2bf(m1 * sc1);
      float bb = m0 * sh0 + m1 * sh1;
      #pragma unroll
      for (int mk = 1; mk < 16; mk <<= 1) bb += __shfl_xor(bb, mk);
      if (l15 == 0) atomicAdd(&bias[b * Cc + o], bb);
    }
  }
}

// ---------------- K4: out = M_b @ v0t + bias + x ----------------
extern "C" __global__ __launch_bounds__(256, 2) void k4_proj(
    const uint16_t* __restrict__ Mp16, const uint16_t* __restrict__ v0t,
    const float* __restrict__ bias, const float* __restrict__ x,
    float* __restrict__ out)
{
  const int tid = threadIdx.x;
  const int lane = tid & 63, wid = tid >> 6;
  const int l15 = lane & 15, lg = lane >> 4;
  const int nb = blockIdx.x, b = blockIdx.y;
  const int nbase = nb * 64, wrow = wid * 64;

  const f32x4 fz = {0.f, 0.f, 0.f, 0.f};
  f32x4 acc[4][4];
  #pragma unroll
  for (int mi = 0; mi < 4; ++mi)
    #pragma unroll
    for (int ni = 0; ni < 4; ++ni) acc[mi][ni] = fz;

  for (int kc = 0; kc < 256; kc += 32){
    s16x8 bf[4];
    #pragma unroll
    for (int ni = 0; ni < 4; ++ni)
      bf[ni] = *(const s16x8*)&v0t[((size_t)(b * Nc + nbase + ni * 16 + l15)) * Cc + kc + lg * 8];
    #pragma unroll
    for (int mi = 0; mi < 4; ++mi){
      s16x8 af = *(const s16x8*)&Mp16[((size_t)(b * Cc + wrow + mi * 16 + l15)) * Cc + kc + lg * 8];
      #pragma unroll
      for (int ni = 0; ni < 4; ++ni)
        acc[mi][ni] = MFMA16(af, bf[ni], acc[mi][ni]);
    }
  }

  #pragma unroll
  for (int mi = 0; mi < 4; ++mi){
    #pragma unroll
    for (int r = 0; r < 4; ++r){
      const int o = wrow + mi * 16 + lg * 4 + r;
      const float bb = bias[b * Cc + o];
      const size_t base = ((size_t)(b * Cc + o)) * Nc + nbase;
      #pragma unroll
      for (int ni = 0; ni < 4; ++ni){
        const size_t aidx = base + ni * 16 + l15;
        out[aidx] = acc[mi][ni][r] + bb + x[aidx];
      }
    }
  }
}

// ---------------- launch ----------------
extern "C" void kernel_launch(void* const* d_in, const int* in_sizes, int n_in,
                              void* d_out, int out_size, void* d_ws, size_t ws_size,
                              hipStream_t stream)
{
  (void)in_sizes; (void)n_in; (void)out_size; (void)ws_size;
  const float* x      = (const float*)d_in[0];
  const float* q_w    = (const float*)d_in[1];
  const float* k_w    = (const float*)d_in[2];
  const float* v_w    = (const float*)d_in[3];
  const float* proj_w = (const float*)d_in[4];
  const float* gamma  = (const float*)d_in[5];
  const float* beta   = (const float*)d_in[6];
  const float* q_vth  = (const float*)d_in[7];
  const float* k_vth  = (const float*)d_in[8];
  float* out = (float*)d_out;

  char* ws = (char*)d_ws;
  uint16_t* qwh = (uint16_t*)(ws + 0);
  uint16_t* qwl = (uint16_t*)(ws + 131072);
  uint16_t* kwh = (uint16_t*)(ws + 262144);
  uint16_t* kwl = (uint16_t*)(ws + 393216);
  uint16_t* vwb = (uint16_t*)(ws + 524288);
  uint16_t* v0t = (uint16_t*)(ws + 655360);           // 32 MiB -> 34209792
  float* psum   = (float*)(ws + 34209792);            // 2 MiB  -> 36306944
  float* psq    = (float*)(ws + 36306944);            // 2 MiB  -> 38404096
  float* Sbuf   = (float*)(ws + 34209792);            // 4 MiB, aliases psum+psq (used after k2)
  float* sc     = (float*)(ws + 38404096);            // 1 KiB
  float* sh     = (float*)(ws + 38405120);            // 1 KiB
  uint16_t* Mp16= (uint16_t*)(ws + 38406144);         // 2 MiB  -> 40503296
  float* bias   = (float*)(ws + 40503296);            // 16 KiB -> 40519680

  // qs/ks live in d_out (64 MiB) as scratch; K4 overwrites d_out last.
  uint16_t* qs = (uint16_t*)d_out;
  uint16_t* ks = (uint16_t*)((char*)d_out + 33554432);

  hipMemsetAsync(bias, 0, 16 * 256 * sizeof(float), stream);

  k0_prep<<<256, 256, 0, stream>>>(q_w, k_w, v_w, qwh, qwl, kwh, kwl, vwb);
  k1_qkv<<<dim3(128, 2, 16), 256, 0, stream>>>(x, qwh, qwl, kwh, kwl, vwb,
                                               q_vth, k_vth, qs, ks, v0t, psum, psq);
  k2_stats<<<256, 256, 0, stream>>>(psum, psq, gamma, beta, sc, sh);
  k3a_qk<<<dim3(8, 16, 8), 256, 0, stream>>>(qs, ks, Sbuf);
  k3b_sm<<<dim3(8, 16), 256, 0, stream>>>(Sbuf, proj_w, sc, sh, Mp16, bias);
  k4_proj<<<dim3(64, 16), 256, 0, stream>>>(Mp16, v0t, bias, x, out);
}

// Round 11
// 312.492 us; speedup vs baseline: 1.1756x; 1.1756x over previous
//
#include <hip/hip_runtime.h>
#include <hip/hip_bf16.h>
#include <stdint.h>
#include <math.h>

typedef __attribute__((ext_vector_type(4))) float f32x4;
typedef __attribute__((ext_vector_type(8))) short s16x8;

#define MFMA16(a,b,c) __builtin_amdgcn_mfma_f32_16x16x32_bf16((a),(b),(c),0,0,0)

#define Cc 256
#define Nc 4096
#define SCALE_F 0.17677669529663688f

__device__ __forceinline__ uint16_t f2bf(float x){
  uint32_t u = __float_as_uint(x);
  return (uint16_t)((u + 0x7fffu + ((u >> 16) & 1u)) >> 16);
}
__device__ __forceinline__ float bf2f(uint16_t b){
  return __uint_as_float(((uint32_t)b) << 16);
}

// ---------------- K0: split weights into bf16 hi/lo ----------------
extern "C" __global__ __launch_bounds__(256) void k0_prep(
    const float* __restrict__ qw, const float* __restrict__ kw, const float* __restrict__ vw,
    uint16_t* __restrict__ qwh, uint16_t* __restrict__ qwl,
    uint16_t* __restrict__ kwh, uint16_t* __restrict__ kwl,
    uint16_t* __restrict__ vwb)
{
  int i = blockIdx.x * 256 + threadIdx.x;
  float q = qw[i]; uint16_t qh = f2bf(q);
  qwh[i] = qh; qwl[i] = f2bf(q - bf2f(qh));
  float k = kw[i]; uint16_t kh = f2bf(k);
  kwh[i] = kh; kwl[i] = f2bf(k - bf2f(kh));
  vwb[i] = f2bf(vw[i]);
}

// ---------------- K1: fused Q,K,V GEMM + spike + BN partials ----------------
// grid (64 nb, 16 b), 512 threads = 8 waves. Tile: 64 n x 256 o (round-5 geometry,
// which measured 122us vs 198us for the small-tile variant). Wave owns 32 o-rows.
// 2 blocks/CU x 8 waves = 16 waves/CU (2x round-5 occupancy) under VGPR cap 128.
// x tile in LDS fragment-ordered bf16 hi/lo (conflict-free b128 reads, no padding).
extern "C" __global__ __launch_bounds__(512, 4) void k1_qkv(
    const float* __restrict__ x,
    const uint16_t* __restrict__ qwh, const uint16_t* __restrict__ qwl,
    const uint16_t* __restrict__ kwh, const uint16_t* __restrict__ kwl,
    const uint16_t* __restrict__ vwb,
    const float* __restrict__ qvth, const float* __restrict__ kvth,
    uint16_t* __restrict__ qs, uint16_t* __restrict__ ks,
    uint16_t* __restrict__ v0t,
    float* __restrict__ psum, float* __restrict__ psq)
{
  __shared__ __align__(16) uint16_t XS[32768];  // XH=[0:16384) XL=[16384:32768), 64 KiB
  __shared__ float vq_s[256];
  __shared__ float vk_s[256];

  const int tid  = threadIdx.x;
  const int lane = tid & 63, wid = tid >> 6;
  const int l15  = lane & 15, lg = lane >> 4;
  const int nb = blockIdx.x, b = blockIdx.y;
  const int nbase = nb * 64;
  const int wrow = wid * 32;

  if (tid < 256) vq_s[tid] = qvth[tid];
  else           vk_s[tid - 256] = kvth[tid - 256];

  uint16_t* XH = XS;
  uint16_t* XL = XS + 16384;

  // ---- stage x tile (64 n x 256 c): wave wid owns c-group g=wid (32 c) ----
  // element (c = g*32+lg*8+j, n = ni*16+l15) -> XH[((g*4+ni)*64 + lane)*8 + j]
  {
    const int c0 = wid * 32 + lg * 8;
    #pragma unroll
    for (int ni = 0; ni < 4; ++ni){
      const float* xp = x + ((size_t)(b * Cc + c0)) * Nc + nbase + ni * 16 + l15;
      s16x8 vh, vl;
      #pragma unroll
      for (int j = 0; j < 8; ++j){
        float v = xp[(size_t)j * Nc];
        uint16_t h = f2bf(v);
        vh[j] = (short)h;
        vl[j] = (short)f2bf(v - bf2f(h));
      }
      const int U = (wid * 4 + ni) * 64 + lane;
      *(s16x8*)&XH[U * 8] = vh;
      *(s16x8*)&XL[U * 8] = vl;
    }
  }
  __syncthreads();

  const f32x4 fz = {0.f, 0.f, 0.f, 0.f};

  // ---- Q,K phase: 3-pass bf16x2 (hi*hi + hi*lo + lo*hi) ----
  f32x4 accq[2][4], acck[2][4];
  #pragma unroll
  for (int mi = 0; mi < 2; ++mi)
    #pragma unroll
    for (int ni = 0; ni < 4; ++ni){ accq[mi][ni] = fz; acck[mi][ni] = fz; }

  for (int g = 0; g < 8; ++g){
    s16x8 bh[4], bl[4];
    #pragma unroll
    for (int ni = 0; ni < 4; ++ni){
      bh[ni] = *(const s16x8*)&XH[((g * 4 + ni) * 64 + lane) * 8];
      bl[ni] = *(const s16x8*)&XL[((g * 4 + ni) * 64 + lane) * 8];
    }
    #pragma unroll
    for (int mi = 0; mi < 2; ++mi){
      const int wa = (wrow + mi * 16 + l15) * Cc + g * 32 + lg * 8;
      s16x8 aqh = *(const s16x8*)&qwh[wa];
      s16x8 aql = *(const s16x8*)&qwl[wa];
      s16x8 akh = *(const s16x8*)&kwh[wa];
      s16x8 akl = *(const s16x8*)&kwl[wa];
      #pragma unroll
      for (int ni = 0; ni < 4; ++ni){
        accq[mi][ni] = MFMA16(aqh, bh[ni], accq[mi][ni]);
        accq[mi][ni] = MFMA16(aqh, bl[ni], accq[mi][ni]);
        accq[mi][ni] = MFMA16(aql, bh[ni], accq[mi][ni]);
        acck[mi][ni] = MFMA16(akh, bh[ni], acck[mi][ni]);
        acck[mi][ni] = MFMA16(akh, bl[ni], acck[mi][ni]);
        acck[mi][ni] = MFMA16(akl, bh[ni], acck[mi][ni]);
      }
    }
  }
  __syncthreads();   // all waves done reading XL (scratch reuse below)

  // ---- spike epilogue: direct 2B stores (round-5 pattern, measured no write amp) ----
  #pragma unroll
  for (int mi = 0; mi < 2; ++mi){
    #pragma unroll
    for (int r = 0; r < 4; ++r){
      const int o = wrow + mi * 16 + lg * 4 + r;
      const float vq = vq_s[o], vk = vk_s[o];
      uint16_t* qp = qs + ((size_t)(b * Cc + o)) * Nc + nbase;
      uint16_t* kp = ks + ((size_t)(b * Cc + o)) * Nc + nbase;
      #pragma unroll
      for (int ni = 0; ni < 4; ++ni){
        const float aq = accq[mi][ni][r];
        const float ak = acck[mi][ni][r];
        float sq = (aq >= vq ? 1.f : 0.f) - (aq <= -vq ? 1.f : 0.f);
        float sk = (ak >= vk ? 1.f : 0.f) - (ak <= -vk ? 1.f : 0.f);
        qp[ni * 16 + l15] = f2bf(sq);
        kp[ni * 16 + l15] = f2bf(sk);
      }
    }
  }

  // ---- V phase: single-pass bf16 (accq/acck dead -> regs reused) ----
  f32x4 accv[2][4];
  #pragma unroll
  for (int mi = 0; mi < 2; ++mi)
    #pragma unroll
    for (int ni = 0; ni < 4; ++ni) accv[mi][ni] = fz;

  for (int g = 0; g < 8; ++g){
    s16x8 bh[4];
    #pragma unroll
    for (int ni = 0; ni < 4; ++ni)
      bh[ni] = *(const s16x8*)&XH[((g * 4 + ni) * 64 + lane) * 8];
    #pragma unroll
    for (int mi = 0; mi < 2; ++mi){
      s16x8 av = *(const s16x8*)&vwb[(wrow + mi * 16 + l15) * Cc + g * 32 + lg * 8];
      #pragma unroll
      for (int ni = 0; ni < 4; ++ni)
        accv[mi][ni] = MFMA16(av, bh[ni], accv[mi][ni]);
    }
  }

  // ---- BN partials: psum layout [c][bid], bid = b*64+nb (1024 bids) ----
  const int bid = b * 64 + nb;
  #pragma unroll
  for (int mi = 0; mi < 2; ++mi){
    #pragma unroll
    for (int r = 0; r < 4; ++r){
      float s1 = 0.f, s2 = 0.f;
      #pragma unroll
      for (int ni = 0; ni < 4; ++ni){
        const float v = accv[mi][ni][r];
        s1 += v; s2 += v * v;
      }
      #pragma unroll
      for (int mk = 1; mk < 16; mk <<= 1){
        s1 += __shfl_xor(s1, mk);
        s2 += __shfl_xor(s2, mk);
      }
      if (l15 == 0){
        const int o = wrow + mi * 16 + lg * 4 + r;
        psum[(size_t)o * 1024 + bid] = s1;
        psq [(size_t)o * 1024 + bid] = s2;
      }
    }
  }

  // ---- v0t transpose via per-wave XL scratch, 2 mi-passes of [16][64] f32 ----
  {
    float* scrW = (float*)XL + wid * 1024;   // 4 KiB per wave
    #pragma unroll
    for (int mi = 0; mi < 2; ++mi){
      #pragma unroll
      for (int ni = 0; ni < 4; ++ni)
        #pragma unroll
        for (int r = 0; r < 4; ++r)
          scrW[(lg * 4 + r) * 64 + ni * 16 + l15] = accv[mi][ni][r];
      // lane = n' (0..63) reads column n' (16 o-values), stores 32B to v0t
      s16x8 o0, o1;
      #pragma unroll
      for (int k = 0; k < 8; ++k){
        o0[k] = (short)f2bf(scrW[k * 64 + lane]);
        o1[k] = (short)f2bf(scrW[(8 + k) * 64 + lane]);
      }
      uint16_t* dst = v0t + ((size_t)(b * Nc + nbase + lane)) * Cc + wrow + mi * 16;
      *(s16x8*)dst = o0;
      *(s16x8*)(dst + 8) = o1;
    }
  }
}

// ---------------- K2: finalize BN (256 blocks, coalesced, 1024 partials) ----------------
extern "C" __global__ __launch_bounds__(256) void k2_stats(
    const float* __restrict__ psum, const float* __restrict__ psq,
    const float* __restrict__ gamma, const float* __restrict__ beta,
    float* __restrict__ sc, float* __restrict__ sh)
{
  __shared__ float w1[4], w2[4];
  const int c = blockIdx.x;
  const int tid = threadIdx.x;
  f32x4 a0 = *(const f32x4*)(psum + (size_t)c * 1024 + tid * 4);
  f32x4 b0 = *(const f32x4*)(psq  + (size_t)c * 1024 + tid * 4);
  float s1 = a0[0] + a0[1] + a0[2] + a0[3];
  float s2 = b0[0] + b0[1] + b0[2] + b0[3];
  #pragma unroll
  for (int mk = 1; mk < 64; mk <<= 1){
    s1 += __shfl_xor(s1, mk);
    s2 += __shfl_xor(s2, mk);
  }
  if ((tid & 63) == 0){ w1[tid >> 6] = s1; w2[tid >> 6] = s2; }
  __syncthreads();
  if (tid == 0){
    float t1 = w1[0]+w1[1]+w1[2]+w1[3];
    float t2 = w2[0]+w2[1]+w2[2]+w2[3];
    const float inv = 1.f / 65536.f;
    const float mean = t1 * inv;
    const float var  = t2 * inv - mean * mean;
    const float s = gamma[c] * rsqrtf(var + 1e-5f);
    sc[c] = s;
    sh[c] = beta[c] - mean * s;
  }
}

// ---------------- K3a: QK^T partials (exact), n-split, LDS-staged ----------------
// grid (8 h, 16 b, 8 ns), 256 threads (4 waves). Block does 512 n in 2 chunks of 256.
// LDS: 36 KiB (QK staging 32 KiB; partial-combine needs 4*1056 floats = 16.5 KiB).
extern "C" __global__ __launch_bounds__(256) void k3a_qk(
    const uint16_t* __restrict__ qs, const uint16_t* __restrict__ ks,
    float* __restrict__ Sbuf)
{
  __shared__ __align__(16) uint16_t QK[18432];
  const int h = blockIdx.x, b = blockIdx.y, ns = blockIdx.z;
  const int tid = threadIdx.x;
  const int lane = tid & 63, w = tid >> 6;

  uint16_t* qlds = QK;
  uint16_t* klds = QK + 8192;

  const f32x4 fz = {0.f, 0.f, 0.f, 0.f};
  f32x4 acc[2][2] = {{fz, fz}, {fz, fz}};
  const uint16_t* qb = qs + ((size_t)(b * Cc + h * 32)) * Nc;
  const uint16_t* kb = ks + ((size_t)(b * Cc + h * 32)) * Nc;

  const int row = tid & 31, seg = tid >> 5;
  for (int cc = 0; cc < 2; ++cc){
    const int n0 = ns * 512 + cc * 256;
    const uint16_t* qsrc = qb + (size_t)row * Nc + n0 + seg * 32;
    const uint16_t* ksrc = kb + (size_t)row * Nc + n0 + seg * 32;
    #pragma unroll
    for (int i = 0; i < 4; ++i){
      const int U = (seg * 2 + (row >> 4)) * 64 + (row & 15) + i * 16;
      *(s16x8*)&qlds[U * 8] = *(const s16x8*)(qsrc + i * 8);
      *(s16x8*)&klds[U * 8] = *(const s16x8*)(ksrc + i * 8);
    }
    __syncthreads();
    #pragma unroll
    for (int kci = 0; kci < 2; ++kci){
      const int g = w * 2 + kci;
      s16x8 a0 = *(const s16x8*)&qlds[((g * 2 + 0) * 64 + lane) * 8];
      s16x8 a1 = *(const s16x8*)&qlds[((g * 2 + 1) * 64 + lane) * 8];
      s16x8 b0 = *(const s16x8*)&klds[((g * 2 + 0) * 64 + lane) * 8];
      s16x8 b1 = *(const s16x8*)&klds[((g * 2 + 1) * 64 + lane) * 8];
      acc[0][0] = MFMA16(a0, b0, acc[0][0]);
      acc[0][1] = MFMA16(a0, b1, acc[0][1]);
      acc[1][0] = MFMA16(a1, b0, acc[1][0]);
      acc[1][1] = MFMA16(a1, b1, acc[1][1]);
    }
    __syncthreads();
  }

  float* Sp = (float*)QK;
  const int l15 = lane & 15, lg = lane >> 4;
  #pragma unroll
  for (int di = 0; di < 2; ++di)
    #pragma unroll
    for (int ei = 0; ei < 2; ++ei)
      #pragma unroll
      for (int r = 0; r < 4; ++r)
        Sp[w * 1056 + (di * 16 + lg * 4 + r) * 33 + ei * 16 + l15] = acc[di][ei][r];
  __syncthreads();
  for (int idx = tid; idx < 1024; idx += 256){
    const int d = idx >> 5, e = idx & 31;
    float s = Sp[0 * 1056 + d * 33 + e] + Sp[1 * 1056 + d * 33 + e]
            + Sp[2 * 1056 + d * 33 + e] + Sp[3 * 1056 + d * 33 + e];
    Sbuf[((size_t)(ns * 128 + b * 8 + h)) * 1024 + idx] = s;
  }
}

// ---------------- K3b: sum partials + softmax + fold into M(bf16), bias ----------------
extern "C" __global__ __launch_bounds__(256) void k3b_sm(
    const float* __restrict__ Sbuf, const float* __restrict__ pw,
    const float* __restrict__ sc, const float* __restrict__ sh,
    uint16_t* __restrict__ Mp16, float* __restrict__ bias)
{
  __shared__ float Sf[32 * 33];
  __shared__ __align__(16) uint16_t attn_t[32 * 40];

  const int h = blockIdx.x, b = blockIdx.y;
  const int tid = threadIdx.x;
  const int lane = tid & 63, w = tid >> 6;
  const int l15 = lane & 15, lg = lane >> 4;

  for (int idx = tid; idx < 1024; idx += 256){
    float s = 0.f;
    #pragma unroll
    for (int ns = 0; ns < 8; ++ns)
      s += Sbuf[((size_t)(ns * 128 + b * 8 + h)) * 1024 + idx];
    Sf[(idx >> 5) * 33 + (idx & 31)] = s * SCALE_F;
  }
  __syncthreads();

  if (tid < 32){
    const int d = tid;
    float mx = -1e30f;
    #pragma unroll
    for (int e = 0; e < 32; ++e) mx = fmaxf(mx, Sf[d * 33 + e]);
    float p[32]; float sum = 0.f;
    #pragma unroll
    for (int e = 0; e < 32; ++e){ p[e] = expf(Sf[d * 33 + e] - mx); sum += p[e]; }
    const float inv = 1.f / sum;
    #pragma unroll
    for (int e = 0; e < 32; ++e) attn_t[e * 40 + d] = f2bf(p[e] * inv);
  }
  __syncthreads();

  s16x8 bfr[2];
  #pragma unroll
  for (int ei = 0; ei < 2; ++ei)
    bfr[ei] = *(const s16x8*)&attn_t[(ei * 16 + l15) * 40 + lg * 8];

  const f32x4 fz = {0.f, 0.f, 0.f, 0.f};
  f32x4 m[4][2];
  #pragma unroll
  for (int mi = 0; mi < 4; ++mi){
    m[mi][0] = fz; m[mi][1] = fz;
    const float* ap = pw + ((size_t)(w * 64 + mi * 16 + l15)) * Cc + h * 32 + lg * 8;
    f32x4 a0 = *(const f32x4*)ap;
    f32x4 a1 = *(const f32x4*)(ap + 4);
    s16x8 af;
    #pragma unroll
    for (int j = 0; j < 4; ++j){ af[j] = (short)f2bf(a0[j]); af[4 + j] = (short)f2bf(a1[j]); }
    #pragma unroll
    for (int ei = 0; ei < 2; ++ei)
      m[mi][ei] = MFMA16(af, bfr[ei], m[mi][ei]);
  }

  const float sc0 = sc[h * 32 + l15],      sc1 = sc[h * 32 + 16 + l15];
  const float sh0 = sh[h * 32 + l15],      sh1 = sh[h * 32 + 16 + l15];
  #pragma unroll
  for (int mi = 0; mi < 4; ++mi){
    #pragma unroll
    for (int r = 0; r < 4; ++r){
      const int o = w * 64 + mi * 16 + lg * 4 + r;
      uint16_t* mp = Mp16 + ((size_t)(b * Cc + o)) * Cc + h * 32;
      const float m0 = m[mi][0][r], m1 = m[mi][1][r];
      mp[l15]      = f2bf(m0 * sc0);
      mp[16 + l15] = f2bf(m1 * sc1);
      float bb = m0 * sh0 + m1 * sh1;
      #pragma unroll
      for (int mk = 1; mk < 16; mk <<= 1) bb += __shfl_xor(bb, mk);
      if (l15 == 0) atomicAdd(&bias[b * Cc + o], bb);
    }
  }
}

// ---------------- K4: out = M_b @ v0t + bias + x ----------------
extern "C" __global__ __launch_bounds__(256, 2) void k4_proj(
    const uint16_t* __restrict__ Mp16, const uint16_t* __restrict__ v0t,
    const float* __restrict__ bias, const float* __restrict__ x,
    float* __restrict__ out)
{
  const int tid = threadIdx.x;
  const int lane = tid & 63, wid = tid >> 6;
  const int l15 = lane & 15, lg = lane >> 4;
  const int nb = blockIdx.x, b = blockIdx.y;
  const int nbase = nb * 64, wrow = wid * 64;

  const f32x4 fz = {0.f, 0.f, 0.f, 0.f};
  f32x4 acc[4][4];
  #pragma unroll
  for (int mi = 0; mi < 4; ++mi)
    #pragma unroll
    for (int ni = 0; ni < 4; ++ni) acc[mi][ni] = fz;

  for (int kc = 0; kc < 256; kc += 32){
    s16x8 bf[4];
    #pragma unroll
    for (int ni = 0; ni < 4; ++ni)
      bf[ni] = *(const s16x8*)&v0t[((size_t)(b * Nc + nbase + ni * 16 + l15)) * Cc + kc + lg * 8];
    #pragma unroll
    for (int mi = 0; mi < 4; ++mi){
      s16x8 af = *(const s16x8*)&Mp16[((size_t)(b * Cc + wrow + mi * 16 + l15)) * Cc + kc + lg * 8];
      #pragma unroll
      for (int ni = 0; ni < 4; ++ni)
        acc[mi][ni] = MFMA16(af, bf[ni], acc[mi][ni]);
    }
  }

  #pragma unroll
  for (int mi = 0; mi < 4; ++mi){
    #pragma unroll
    for (int r = 0; r < 4; ++r){
      const int o = wrow + mi * 16 + lg * 4 + r;
      const float bb = bias[b * Cc + o];
      const size_t base = ((size_t)(b * Cc + o)) * Nc + nbase;
      #pragma unroll
      for (int ni = 0; ni < 4; ++ni){
        const size_t aidx = base + ni * 16 + l15;
        out[aidx] = acc[mi][ni][r] + bb + x[aidx];
      }
    }
  }
}

// ---------------- launch ----------------
extern "C" void kernel_launch(void* const* d_in, const int* in_sizes, int n_in,
                              void* d_out, int out_size, void* d_ws, size_t ws_size,
                              hipStream_t stream)
{
  (void)in_sizes; (void)n_in; (void)out_size; (void)ws_size;
  const float* x      = (const float*)d_in[0];
  const float* q_w    = (const float*)d_in[1];
  const float* k_w    = (const float*)d_in[2];
  const float* v_w    = (const float*)d_in[3];
  const float* proj_w = (const float*)d_in[4];
  const float* gamma  = (const float*)d_in[5];
  const float* beta   = (const float*)d_in[6];
  const float* q_vth  = (const float*)d_in[7];
  const float* k_vth  = (const float*)d_in[8];
  float* out = (float*)d_out;

  char* ws = (char*)d_ws;
  uint16_t* qwh = (uint16_t*)(ws + 0);
  uint16_t* qwl = (uint16_t*)(ws + 131072);
  uint16_t* kwh = (uint16_t*)(ws + 262144);
  uint16_t* kwl = (uint16_t*)(ws + 393216);
  uint16_t* vwb = (uint16_t*)(ws + 524288);
  uint16_t* v0t = (uint16_t*)(ws + 655360);           // 32 MiB -> 34209792
  float* psum   = (float*)(ws + 34209792);            // 1 MiB (256 x 1024)
  float* psq    = (float*)(ws + 36306944);            // 1 MiB
  float* Sbuf   = (float*)(ws + 34209792);            // 4 MiB, aliases psum+psq (used after k2)
  float* sc     = (float*)(ws + 38404096);            // 1 KiB
  float* sh     = (float*)(ws + 38405120);            // 1 KiB
  uint16_t* Mp16= (uint16_t*)(ws + 38406144);         // 2 MiB
  float* bias   = (float*)(ws + 40503296);            // 16 KiB

  // qs/ks live in d_out (64 MiB) as scratch; K4 overwrites d_out last.
  uint16_t* qs = (uint16_t*)d_out;
  uint16_t* ks = (uint16_t*)((char*)d_out + 33554432);

  hipMemsetAsync(bias, 0, 16 * 256 * sizeof(float), stream);

  k0_prep<<<256, 256, 0, stream>>>(q_w, k_w, v_w, qwh, qwl, kwh, kwl, vwb);
  k1_qkv<<<dim3(64, 16), 512, 0, stream>>>(x, qwh, qwl, kwh, kwl, vwb,
                                           q_vth, k_vth, qs, ks, v0t, psum, psq);
  k2_stats<<<256, 256, 0, stream>>>(psum, psq, gamma, beta, sc, sh);
  k3a_qk<<<dim3(8, 16, 8), 256, 0, stream>>>(qs, ks, Sbuf);
  k3b_sm<<<dim3(8, 16), 256, 0, stream>>>(Sbuf, proj_w, sc, sh, Mp16, bias);
  k4_proj<<<dim3(64, 16), 256, 0, stream>>>(Mp16, v0t, bias, x, out);
}